// Round 2
// baseline (1301.875 us; speedup 1.0000x reference)
//
#include <hip/hip_runtime.h>
#include <hip/hip_bf16.h>

// 2-layer GCN (PyG GCNConv) on MI355X.
// R2: replace exact-CSR build (k_fill: 110us, 107MB scattered-write amplification)
// with bucket partition + LDS-atomic aggregation.
//
// Pipeline:
//   1. k_hist: per-block bucket histogram (LDS) + global in-degree histogram
//   2. k_dinv: dinv = rsqrt(deg+1)
//   3. scan of [bucket][block] count matrix -> partition offsets
//   4. k_partition: edges -> bucket-grouped packed words (src<<8 | local_dst)
//   5. k_gemm1: g1 = (x @ W1) * dinv[row]        (LDS fp32 GEMM)
//   6. k_agg1: per-bucket LDS accumulator, edge-parallel; epilogue adds
//      self-loop, *dinv[d], +b1, relu -> t1
//   7. k_gemm2: g2 = (t1 @ W2) * dinv[row]
//   8. k_agg2: same for layer 2 (32 feats, 2 edges/wave-iter) -> out
//
// Bucket = 256 nodes (shift 8). Partition block = 8192 edges.

#define IN_DIM 128
#define HID_DIM 64
#define OUT_DIM 32
#define BSHIFT 8
#define BSIZE 256
#define BMASK 255
#define PEB 8192   // edges per partition block

// ---------------------------------------------------------------- pass 1
__global__ __launch_bounds__(256) void k_hist(const int* __restrict__ dst, int E,
                                              int* __restrict__ deg,
                                              int* __restrict__ mat, int B, int nPB) {
    __shared__ int cnt[512];
    int t = threadIdx.x;
    for (int b = t; b < B; b += 256) cnt[b] = 0;
    __syncthreads();
    int base = blockIdx.x * PEB;
#pragma unroll
    for (int i = 0; i < PEB / 256; ++i) {
        int e = base + i * 256 + t;
        if (e < E) {
            int d = dst[e];
            atomicAdd(&deg[d], 1);
            atomicAdd(&cnt[d >> BSHIFT], 1);
        }
    }
    __syncthreads();
    for (int b = t; b < B; b += 256) mat[b * nPB + blockIdx.x] = cnt[b];
}

__global__ void k_dinv(const int* __restrict__ deg, float* __restrict__ dinv, int N) {
    int i = blockIdx.x * 256 + threadIdx.x;
    if (i < N) dinv[i] = rsqrtf((float)deg[i] + 1.0f);
}

// ---------------------------------------------------------------- scan (2-level)
__global__ void k_chunk_sums(const int* __restrict__ arr, int M, int* __restrict__ sums) {
    __shared__ int sdata[256];
    int t = threadIdx.x;
    int base = blockIdx.x * 1024 + t * 4;
    int s = 0;
#pragma unroll
    for (int i = 0; i < 4; ++i) {
        int idx = base + i;
        if (idx < M) s += arr[idx];
    }
    sdata[t] = s;
    __syncthreads();
    for (int off = 128; off > 0; off >>= 1) {
        if (t < off) sdata[t] += sdata[t + off];
        __syncthreads();
    }
    if (t == 0) sums[blockIdx.x] = sdata[0];
}

__global__ void k_scan_sums(int* __restrict__ sums, int nchunks) {
    __shared__ int buf[1024];
    int t = threadIdx.x;  // 1024 threads
    int v = (t < nchunks) ? sums[t] : 0;
    buf[t] = v;
    __syncthreads();
    for (int off = 1; off < 1024; off <<= 1) {
        int x = (t >= off) ? buf[t - off] : 0;
        __syncthreads();
        buf[t] += x;
        __syncthreads();
    }
    if (t < nchunks) sums[t] = buf[t] - v;  // exclusive
}

__global__ void k_scan_chunks(const int* __restrict__ arr, int M,
                              const int* __restrict__ sums, int* __restrict__ out) {
    __shared__ int tsum[256];
    int t = threadIdx.x;
    int idx0 = blockIdx.x * 1024 + t * 4;
    int v[4];
    int s = 0;
#pragma unroll
    for (int i = 0; i < 4; ++i) {
        int idx = idx0 + i;
        v[i] = (idx < M) ? arr[idx] : 0;
        s += v[i];
    }
    tsum[t] = s;
    __syncthreads();
    int mine = s;
    for (int off = 1; off < 256; off <<= 1) {
        int x = (t >= off) ? tsum[t - off] : 0;
        __syncthreads();
        tsum[t] += x;
        __syncthreads();
    }
    int run = tsum[t] - mine + sums[blockIdx.x];
#pragma unroll
    for (int i = 0; i < 4; ++i) {
        int idx = idx0 + i;
        if (idx < M) out[idx] = run;
        run += v[i];
    }
}

// ---------------------------------------------------------------- pass 2: partition
__global__ __launch_bounds__(256) void k_partition(const int* __restrict__ src,
                                                   const int* __restrict__ dst, int E,
                                                   const int* __restrict__ mats,
                                                   unsigned* __restrict__ packed,
                                                   int B, int nPB) {
    __shared__ int off[512];
    int t = threadIdx.x;
    for (int b = t; b < B; b += 256) off[b] = mats[b * nPB + blockIdx.x];
    __syncthreads();
    int base = blockIdx.x * PEB;
#pragma unroll
    for (int i = 0; i < PEB / 256; ++i) {
        int e = base + i * 256 + t;
        if (e < E) {
            int d = dst[e];
            int s = src[e];
            int slot = atomicAdd(&off[d >> BSHIFT], 1);
            packed[slot] = ((unsigned)s << BSHIFT) | (unsigned)(d & BMASK);
        }
    }
}

// ---------------------------------------------------------------- GEMM1: g1 = (x @ W1) * dinv
__global__ __launch_bounds__(256) void k_gemm1(const float* __restrict__ x,
                                               const float* __restrict__ W,
                                               const float* __restrict__ dinv,
                                               float* __restrict__ g1, int N) {
    __shared__ float xs[64 * 128];
    __shared__ float ws[128 * 64];
    int t = threadIdx.x;
    int row0 = blockIdx.x * 64;

    const float4* W4 = (const float4*)W;
    float4* ws4 = (float4*)ws;
#pragma unroll
    for (int i = 0; i < 8; ++i) ws4[t + 256 * i] = W4[t + 256 * i];
#pragma unroll
    for (int i = 0; i < 8; ++i) {
        int l = t + 256 * i;
        int r = l >> 5;
        int c4 = l & 31;
        int row = row0 + r;
        float4 val = make_float4(0.f, 0.f, 0.f, 0.f);
        if (row < N) val = ((const float4*)(x + (size_t)row * IN_DIM))[c4];
        *(float4*)&xs[r * IN_DIM + c4 * 4] = val;
    }
    __syncthreads();

    int tx = t & 15;
    int ty = t >> 4;
    float acc[4][4] = {};
    for (int k = 0; k < 128; k += 4) {
        float a[4][4], b[4][4];
#pragma unroll
        for (int i = 0; i < 4; ++i)
            *(float4*)a[i] = *(const float4*)&xs[(ty * 4 + i) * IN_DIM + k];
#pragma unroll
        for (int kk = 0; kk < 4; ++kk)
            *(float4*)b[kk] = *(const float4*)&ws[(k + kk) * HID_DIM + tx * 4];
#pragma unroll
        for (int i = 0; i < 4; ++i)
#pragma unroll
            for (int kk = 0; kk < 4; ++kk)
#pragma unroll
                for (int j = 0; j < 4; ++j)
                    acc[i][j] += a[i][kk] * b[kk][j];
    }
#pragma unroll
    for (int i = 0; i < 4; ++i) {
        int row = row0 + ty * 4 + i;
        if (row < N) {
            float dv = dinv[row];
            float4 r;
            r.x = acc[i][0] * dv; r.y = acc[i][1] * dv;
            r.z = acc[i][2] * dv; r.w = acc[i][3] * dv;
            ((float4*)(g1 + (size_t)row * HID_DIM))[tx] = r;
        }
    }
}

// ---------------------------------------------------------------- GEMM2: g2 = (t1 @ W2) * dinv
__global__ __launch_bounds__(256) void k_gemm2(const float* __restrict__ t1,
                                               const float* __restrict__ W,
                                               const float* __restrict__ dinv,
                                               float* __restrict__ g2, int N) {
    __shared__ float xs[64 * 68];
    __shared__ float ws[64 * 32];
    int t = threadIdx.x;
    int row0 = blockIdx.x * 64;

    const float4* W4 = (const float4*)W;
    float4* ws4 = (float4*)ws;
#pragma unroll
    for (int i = 0; i < 2; ++i) ws4[t + 256 * i] = W4[t + 256 * i];
#pragma unroll
    for (int i = 0; i < 4; ++i) {
        int l = t + 256 * i;
        int r = l >> 4;
        int c4 = l & 15;
        int row = row0 + r;
        float4 val = make_float4(0.f, 0.f, 0.f, 0.f);
        if (row < N) val = ((const float4*)(t1 + (size_t)row * HID_DIM))[c4];
        *(float4*)&xs[r * 68 + c4 * 4] = val;
    }
    __syncthreads();

    int tx = t & 7;
    int ty = t >> 3;
    float acc[2][4] = {};
    for (int k = 0; k < 64; k += 4) {
        float a[2][4], b[4][4];
#pragma unroll
        for (int i = 0; i < 2; ++i)
            *(float4*)a[i] = *(const float4*)&xs[(ty * 2 + i) * 68 + k];
#pragma unroll
        for (int kk = 0; kk < 4; ++kk)
            *(float4*)b[kk] = *(const float4*)&ws[(k + kk) * OUT_DIM + tx * 4];
#pragma unroll
        for (int i = 0; i < 2; ++i)
#pragma unroll
            for (int kk = 0; kk < 4; ++kk)
#pragma unroll
                for (int j = 0; j < 4; ++j)
                    acc[i][j] += a[i][kk] * b[kk][j];
    }
#pragma unroll
    for (int i = 0; i < 2; ++i) {
        int row = row0 + ty * 2 + i;
        if (row < N) {
            float dv = dinv[row];
            float4 r;
            r.x = acc[i][0] * dv; r.y = acc[i][1] * dv;
            r.z = acc[i][2] * dv; r.w = acc[i][3] * dv;
            ((float4*)(g2 + (size_t)row * OUT_DIM))[tx] = r;
        }
    }
}

// ---------------------------------------------------------------- agg layer 1
// One block per bucket (256 nodes x 64 feats = 64KB LDS acc). Edge-parallel:
// wave reads 64 packed words (coalesced), broadcasts each via readlane;
// per edge: one coalesced 256B g1 row read + conflict-free LDS float atomicAdd.
__global__ __launch_bounds__(256) void k_agg1(const float* __restrict__ g1,
                                              const unsigned* __restrict__ packed,
                                              const int* __restrict__ mats,
                                              const float* __restrict__ dinv,
                                              const float* __restrict__ b1,
                                              float* __restrict__ t1,
                                              int N, int E, int B, int nPB) {
    __shared__ float acc[BSIZE * HID_DIM];  // 64KB
    int t = threadIdx.x;
    int bkt = blockIdx.x;
    // zero acc
    float4* a4 = (float4*)acc;
#pragma unroll
    for (int i = 0; i < (BSIZE * HID_DIM / 4) / 256; ++i)
        a4[t + 256 * i] = make_float4(0.f, 0.f, 0.f, 0.f);
    __syncthreads();

    int beg = mats[bkt * nPB];
    int end = (bkt + 1 < B) ? mats[(bkt + 1) * nPB] : E;
    int wid = t >> 6, lane = t & 63;

    int base = beg + wid * 64;
    for (; base + 64 <= end; base += 256) {
        unsigned w = packed[base + lane];
#pragma unroll 16
        for (int j = 0; j < 64; ++j) {
            unsigned wj = (unsigned)__builtin_amdgcn_readlane((int)w, j);
            int s = wj >> BSHIFT;
            int ld = wj & BMASK;
            float v = g1[(size_t)s * HID_DIM + lane];
            atomicAdd(&acc[(ld << 6) + lane], v);
        }
    }
    if (base < end) {  // tail chunk (uniform cnt per wave)
        int cnt = end - base;
        unsigned w = (lane < cnt) ? packed[base + lane] : 0u;
        for (int j = 0; j < cnt; ++j) {
            unsigned wj = (unsigned)__builtin_amdgcn_readlane((int)w, j);
            int s = wj >> BSHIFT;
            int ld = wj & BMASK;
            float v = g1[(size_t)s * HID_DIM + lane];
            atomicAdd(&acc[(ld << 6) + lane], v);
        }
    }
    __syncthreads();

    // epilogue: self-loop + dinv[d]*acc + b1, relu
    int node0 = bkt << BSHIFT;
    for (int i = t; i < BSIZE * HID_DIM; i += 256) {
        int ld = i >> 6, f = i & 63;
        int d = node0 + ld;
        if (d < N) {
            float v = dinv[d] * (acc[i] + g1[(size_t)d * HID_DIM + f]) + b1[f];
            t1[(size_t)d * HID_DIM + f] = v > 0.f ? v : 0.f;
        }
    }
}

// ---------------------------------------------------------------- agg layer 2
// 32 feats: each wave-iter handles 2 edges (lanes 0-31 / 32-63).
__global__ __launch_bounds__(256) void k_agg2(const float* __restrict__ g2,
                                              const unsigned* __restrict__ packed,
                                              const int* __restrict__ mats,
                                              const float* __restrict__ dinv,
                                              const float* __restrict__ b2,
                                              float* __restrict__ out,
                                              int N, int E, int B, int nPB) {
    __shared__ float acc[BSIZE * OUT_DIM];  // 32KB
    int t = threadIdx.x;
    int bkt = blockIdx.x;
    float4* a4 = (float4*)acc;
#pragma unroll
    for (int i = 0; i < (BSIZE * OUT_DIM / 4) / 256; ++i)
        a4[t + 256 * i] = make_float4(0.f, 0.f, 0.f, 0.f);
    __syncthreads();

    int beg = mats[bkt * nPB];
    int end = (bkt + 1 < B) ? mats[(bkt + 1) * nPB] : E;
    int wid = t >> 6, lane = t & 63;
    int e2 = lane >> 5, f = lane & 31;

    int base = beg + wid * 64;
    for (; base + 64 <= end; base += 256) {
        unsigned w = packed[base + lane];
#pragma unroll 8
        for (int j = 0; j < 32; ++j) {
            unsigned w0 = (unsigned)__builtin_amdgcn_readlane((int)w, 2 * j);
            unsigned w1 = (unsigned)__builtin_amdgcn_readlane((int)w, 2 * j + 1);
            unsigned we = e2 ? w1 : w0;
            int s = we >> BSHIFT;
            int ld = we & BMASK;
            float v = g2[(size_t)s * OUT_DIM + f];
            atomicAdd(&acc[(ld << 5) + f], v);
        }
    }
    if (base < end) {
        int cnt = end - base;
        unsigned w = (lane < cnt) ? packed[base + lane] : 0u;
        int npair = (cnt + 1) >> 1;
        for (int j = 0; j < npair; ++j) {
            unsigned w0 = (unsigned)__builtin_amdgcn_readlane((int)w, 2 * j);
            unsigned w1 = (unsigned)__builtin_amdgcn_readlane((int)w,
                              (2 * j + 1 < cnt) ? 2 * j + 1 : 2 * j);
            unsigned we = e2 ? w1 : w0;
            bool act = (2 * j + e2) < cnt;
            if (act) {
                int s = we >> BSHIFT;
                int ld = we & BMASK;
                float v = g2[(size_t)s * OUT_DIM + f];
                atomicAdd(&acc[(ld << 5) + f], v);
            }
        }
    }
    __syncthreads();

    int node0 = bkt << BSHIFT;
    for (int i = t; i < BSIZE * OUT_DIM; i += 256) {
        int ld = i >> 5, ff = i & 31;
        int d = node0 + ld;
        if (d < N) {
            out[(size_t)d * OUT_DIM + ff] =
                dinv[d] * (acc[i] + g2[(size_t)d * OUT_DIM + ff]) + b2[ff];
        }
    }
}

// ---------------------------------------------------------------- launch
extern "C" void kernel_launch(void* const* d_in, const int* in_sizes, int n_in,
                              void* d_out, int out_size, void* d_ws, size_t ws_size,
                              hipStream_t stream) {
    const float* x  = (const float*)d_in[0];
    const int*   ei = (const int*)d_in[1];
    const float* W1 = (const float*)d_in[2];
    const float* b1 = (const float*)d_in[3];
    const float* W2 = (const float*)d_in[4];
    const float* b2 = (const float*)d_in[5];
    float* out = (float*)d_out;

    const int N = in_sizes[0] / IN_DIM;
    const int E = in_sizes[1] / 2;
    const int* src = ei;
    const int* dst = ei + E;

    const int B   = (N + BSIZE - 1) / BSIZE;       // buckets
    const int nPB = (E + PEB - 1) / PEB;           // partition blocks
    const int M   = B * nPB;                       // count matrix
    const int nchunks = (M + 1023) / 1024;

    char* p = (char*)d_ws;
    auto alloc = [&](size_t bytes) -> void* {
        void* r = (void*)p;
        p += (bytes + 255) & ~(size_t)255;
        return r;
    };
    int*      deg    = (int*)alloc((size_t)N * 4);
    float*    dinv   = (float*)alloc((size_t)N * 4);
    int*      mat    = (int*)alloc((size_t)M * 4);
    int*      mats   = (int*)alloc((size_t)M * 4);
    int*      sums   = (int*)alloc((size_t)nchunks * 4);
    unsigned* packed = (unsigned*)alloc((size_t)E * 4);
    float*    g1     = (float*)alloc((size_t)N * HID_DIM * 4);
    float*    t1     = (float*)alloc((size_t)N * HID_DIM * 4);
    float*    g2     = (float*)alloc((size_t)N * OUT_DIM * 4);

    hipMemsetAsync(deg, 0, (size_t)N * 4, stream);
    k_hist<<<nPB, 256, 0, stream>>>(dst, E, deg, mat, B, nPB);
    k_dinv<<<(N + 255) / 256, 256, 0, stream>>>(deg, dinv, N);
    k_chunk_sums<<<nchunks, 256, 0, stream>>>(mat, M, sums);
    k_scan_sums<<<1, 1024, 0, stream>>>(sums, nchunks);
    k_scan_chunks<<<nchunks, 256, 0, stream>>>(mat, M, sums, mats);
    k_partition<<<nPB, 256, 0, stream>>>(src, dst, E, mats, packed, B, nPB);

    k_gemm1<<<(N + 63) / 64, 256, 0, stream>>>(x, W1, dinv, g1, N);
    k_agg1<<<B, 256, 0, stream>>>(g1, packed, mats, dinv, b1, t1, N, E, B, nPB);
    k_gemm2<<<(N + 63) / 64, 256, 0, stream>>>(t1, W2, dinv, g2, N);
    k_agg2<<<B, 256, 0, stream>>>(g2, packed, mats, dinv, b2, out, N, E, B, nPB);
}

// Round 3
// 315.480 us; speedup vs baseline: 4.1266x; 4.1266x over previous
//
#include <hip/hip_runtime.h>
#include <hip/hip_bf16.h>

// 2-layer GCN (PyG GCNConv) on MI355X.
// R3: R1's per-node-wave CSR gather (100k independent waves = latency hiding)
// + cheap CSR build via bucket partition (fixes R1 k_fill's 107MB scattered-
// write amplification; avoids R2 agg's readlane serialization @ 2 blocks/CU).
//
// Pipeline:
//   1. k_hist:      per-block bucket histogram (LDS only, no global atomics)
//   2. scan mat[B][nPB] -> mats (partition offsets)
//   3. k_partition: edges -> bucket-grouped packed words (src<<8 | local_dst)
//   4. k_csrfill:   per bucket: LDS local-degree count -> dinv + rowptr,
//                   LDS scan, scatter colidx into the bucket's contiguous
//                   segment (writes L2-local -> no amplification)
//   5. k_gemm1:     g1 = (x @ W1) * dinv[row]
//   6. k_agg1:      one 64-lane wave per node, 4-deep unrolled CSR gather,
//                   epilogue self-loop + dinv*acc + b1 + relu -> t1
//   7. k_gemm2:     g2 = (t1 @ W2) * dinv[row]   (g2 aliases g1 buffer)
//   8. k_agg2:      two nodes per wave (32 lanes each) -> out

#define IN_DIM 128
#define HID_DIM 64
#define OUT_DIM 32
#define BSHIFT 8
#define BSIZE 256
#define BMASK 255
#define PEB 8192   // edges per partition block

// ---------------------------------------------------------------- pass 1: bucket histogram
__global__ __launch_bounds__(256) void k_hist(const int* __restrict__ dst, int E,
                                              int* __restrict__ mat, int B, int nPB) {
    __shared__ int cnt[512];
    int t = threadIdx.x;
    for (int b = t; b < B; b += 256) cnt[b] = 0;
    __syncthreads();
    int base = blockIdx.x * PEB;
#pragma unroll
    for (int i = 0; i < PEB / 256; ++i) {
        int e = base + i * 256 + t;
        if (e < E) atomicAdd(&cnt[dst[e] >> BSHIFT], 1);
    }
    __syncthreads();
    for (int b = t; b < B; b += 256) mat[b * nPB + blockIdx.x] = cnt[b];
}

// ---------------------------------------------------------------- scan (2-level, in-place capable)
__global__ void k_chunk_sums(const int* __restrict__ arr, int M, int* __restrict__ sums) {
    __shared__ int sdata[256];
    int t = threadIdx.x;
    int base = blockIdx.x * 1024 + t * 4;
    int s = 0;
#pragma unroll
    for (int i = 0; i < 4; ++i) {
        int idx = base + i;
        if (idx < M) s += arr[idx];
    }
    sdata[t] = s;
    __syncthreads();
    for (int off = 128; off > 0; off >>= 1) {
        if (t < off) sdata[t] += sdata[t + off];
        __syncthreads();
    }
    if (t == 0) sums[blockIdx.x] = sdata[0];
}

__global__ void k_scan_sums(int* __restrict__ sums, int nchunks) {
    __shared__ int buf[1024];
    int t = threadIdx.x;  // 1024 threads
    int v = (t < nchunks) ? sums[t] : 0;
    buf[t] = v;
    __syncthreads();
    for (int off = 1; off < 1024; off <<= 1) {
        int x = (t >= off) ? buf[t - off] : 0;
        __syncthreads();
        buf[t] += x;
        __syncthreads();
    }
    if (t < nchunks) sums[t] = buf[t] - v;  // exclusive
}

__global__ void k_scan_chunks(const int* __restrict__ arr, int M,
                              const int* __restrict__ sums, int* __restrict__ out) {
    __shared__ int tsum[256];
    int t = threadIdx.x;
    int idx0 = blockIdx.x * 1024 + t * 4;
    int v[4];
    int s = 0;
#pragma unroll
    for (int i = 0; i < 4; ++i) {
        int idx = idx0 + i;
        v[i] = (idx < M) ? arr[idx] : 0;
        s += v[i];
    }
    tsum[t] = s;
    __syncthreads();
    int mine = s;
    for (int off = 1; off < 256; off <<= 1) {
        int x = (t >= off) ? tsum[t - off] : 0;
        __syncthreads();
        tsum[t] += x;
        __syncthreads();
    }
    int run = tsum[t] - mine + sums[blockIdx.x];
#pragma unroll
    for (int i = 0; i < 4; ++i) {
        int idx = idx0 + i;
        if (idx < M) out[idx] = run;
        run += v[i];
    }
}

// ---------------------------------------------------------------- pass 2: partition
__global__ __launch_bounds__(256) void k_partition(const int* __restrict__ src,
                                                   const int* __restrict__ dst, int E,
                                                   const int* __restrict__ mats,
                                                   unsigned* __restrict__ packed,
                                                   int B, int nPB) {
    __shared__ int off[512];
    int t = threadIdx.x;
    for (int b = t; b < B; b += 256) off[b] = mats[b * nPB + blockIdx.x];
    __syncthreads();
    int base = blockIdx.x * PEB;
#pragma unroll
    for (int i = 0; i < PEB / 256; ++i) {
        int e = base + i * 256 + t;
        if (e < E) {
            int d = dst[e];
            int s = src[e];
            int slot = atomicAdd(&off[d >> BSHIFT], 1);
            packed[slot] = ((unsigned)s << BSHIFT) | (unsigned)(d & BMASK);
        }
    }
}

// ---------------------------------------------------------------- pass 3: per-bucket CSR build
// One block per bucket. All colidx writes land in the bucket's contiguous
// segment [base, end) -> combine in L2, no write amplification.
__global__ __launch_bounds__(256) void k_csrfill(const unsigned* __restrict__ packed,
                                                 const int* __restrict__ mats,
                                                 int* __restrict__ colidx,
                                                 int* __restrict__ rowptr,
                                                 float* __restrict__ dinv,
                                                 int N, int E, int B, int nPB) {
    __shared__ int ldeg[256];
    __shared__ int lscan[256];
    __shared__ int sexc[256];
    __shared__ int lfill[256];
    int t = threadIdx.x, bkt = blockIdx.x;
    int base = mats[bkt * nPB];
    int end  = (bkt + 1 < B) ? mats[(bkt + 1) * nPB] : E;
    ldeg[t] = 0;
    __syncthreads();
    for (int e = base + t; e < end; e += 256)
        atomicAdd(&ldeg[packed[e] & BMASK], 1);
    __syncthreads();
    int v = ldeg[t];
    lscan[t] = v;
    __syncthreads();
    for (int off = 1; off < 256; off <<= 1) {
        int x = (t >= off) ? lscan[t - off] : 0;
        __syncthreads();
        lscan[t] += x;
        __syncthreads();
    }
    int exc = lscan[t] - v;
    sexc[t] = exc;
    lfill[t] = 0;
    int node = (bkt << BSHIFT) + t;
    if (node < N) {
        rowptr[node] = base + exc;
        dinv[node] = rsqrtf((float)v + 1.0f);
    }
    if (bkt == B - 1 && t == 0) rowptr[N] = E;
    __syncthreads();
    for (int e = base + t; e < end; e += 256) {
        unsigned w = packed[e];
        int ld = w & BMASK;
        int pos = base + sexc[ld] + atomicAdd(&lfill[ld], 1);
        colidx[pos] = (int)(w >> BSHIFT);
    }
}

// ---------------------------------------------------------------- GEMM1: g1 = (x @ W1) * dinv
__global__ __launch_bounds__(256) void k_gemm1(const float* __restrict__ x,
                                               const float* __restrict__ W,
                                               const float* __restrict__ dinv,
                                               float* __restrict__ g1, int N) {
    __shared__ float xs[64 * 128];
    __shared__ float ws[128 * 64];
    int t = threadIdx.x;
    int row0 = blockIdx.x * 64;

    const float4* W4 = (const float4*)W;
    float4* ws4 = (float4*)ws;
#pragma unroll
    for (int i = 0; i < 8; ++i) ws4[t + 256 * i] = W4[t + 256 * i];
#pragma unroll
    for (int i = 0; i < 8; ++i) {
        int l = t + 256 * i;
        int r = l >> 5;
        int c4 = l & 31;
        int row = row0 + r;
        float4 val = make_float4(0.f, 0.f, 0.f, 0.f);
        if (row < N) val = ((const float4*)(x + (size_t)row * IN_DIM))[c4];
        *(float4*)&xs[r * IN_DIM + c4 * 4] = val;
    }
    __syncthreads();

    int tx = t & 15;
    int ty = t >> 4;
    float acc[4][4] = {};
    for (int k = 0; k < 128; k += 4) {
        float a[4][4], b[4][4];
#pragma unroll
        for (int i = 0; i < 4; ++i)
            *(float4*)a[i] = *(const float4*)&xs[(ty * 4 + i) * IN_DIM + k];
#pragma unroll
        for (int kk = 0; kk < 4; ++kk)
            *(float4*)b[kk] = *(const float4*)&ws[(k + kk) * HID_DIM + tx * 4];
#pragma unroll
        for (int i = 0; i < 4; ++i)
#pragma unroll
            for (int kk = 0; kk < 4; ++kk)
#pragma unroll
                for (int j = 0; j < 4; ++j)
                    acc[i][j] += a[i][kk] * b[kk][j];
    }
#pragma unroll
    for (int i = 0; i < 4; ++i) {
        int row = row0 + ty * 4 + i;
        if (row < N) {
            float dv = dinv[row];
            float4 r;
            r.x = acc[i][0] * dv; r.y = acc[i][1] * dv;
            r.z = acc[i][2] * dv; r.w = acc[i][3] * dv;
            ((float4*)(g1 + (size_t)row * HID_DIM))[tx] = r;
        }
    }
}

// ---------------------------------------------------------------- GEMM2: g2 = (t1 @ W2) * dinv
__global__ __launch_bounds__(256) void k_gemm2(const float* __restrict__ t1,
                                               const float* __restrict__ W,
                                               const float* __restrict__ dinv,
                                               float* __restrict__ g2, int N) {
    __shared__ float xs[64 * 68];
    __shared__ float ws[64 * 32];
    int t = threadIdx.x;
    int row0 = blockIdx.x * 64;

    const float4* W4 = (const float4*)W;
    float4* ws4 = (float4*)ws;
#pragma unroll
    for (int i = 0; i < 2; ++i) ws4[t + 256 * i] = W4[t + 256 * i];
#pragma unroll
    for (int i = 0; i < 4; ++i) {
        int l = t + 256 * i;
        int r = l >> 4;
        int c4 = l & 15;
        int row = row0 + r;
        float4 val = make_float4(0.f, 0.f, 0.f, 0.f);
        if (row < N) val = ((const float4*)(t1 + (size_t)row * HID_DIM))[c4];
        *(float4*)&xs[r * 68 + c4 * 4] = val;
    }
    __syncthreads();

    int tx = t & 7;
    int ty = t >> 3;
    float acc[2][4] = {};
    for (int k = 0; k < 64; k += 4) {
        float a[2][4], b[4][4];
#pragma unroll
        for (int i = 0; i < 2; ++i)
            *(float4*)a[i] = *(const float4*)&xs[(ty * 2 + i) * 68 + k];
#pragma unroll
        for (int kk = 0; kk < 4; ++kk)
            *(float4*)b[kk] = *(const float4*)&ws[(k + kk) * OUT_DIM + tx * 4];
#pragma unroll
        for (int i = 0; i < 2; ++i)
#pragma unroll
            for (int kk = 0; kk < 4; ++kk)
#pragma unroll
                for (int j = 0; j < 4; ++j)
                    acc[i][j] += a[i][kk] * b[kk][j];
    }
#pragma unroll
    for (int i = 0; i < 2; ++i) {
        int row = row0 + ty * 2 + i;
        if (row < N) {
            float dv = dinv[row];
            float4 r;
            r.x = acc[i][0] * dv; r.y = acc[i][1] * dv;
            r.z = acc[i][2] * dv; r.w = acc[i][3] * dv;
            ((float4*)(g2 + (size_t)row * OUT_DIM))[tx] = r;
        }
    }
}

// ---------------------------------------------------------------- agg layer 1
// One 64-lane wave per node; lane = feature. 4-deep unrolled gather keeps
// 4 independent 256B row loads in flight per wave; 100k waves hide latency.
__global__ __launch_bounds__(256) void k_agg1(const float* __restrict__ g1,
                                              const int* __restrict__ rowptr,
                                              const int* __restrict__ colidx,
                                              const float* __restrict__ dinv,
                                              const float* __restrict__ b1,
                                              float* __restrict__ t1, int N) {
    int d = (blockIdx.x * 256 + threadIdx.x) >> 6;
    int lane = threadIdx.x & 63;
    if (d >= N) return;
    float acc = g1[(size_t)d * HID_DIM + lane];  // self-loop
    int beg = rowptr[d], end = rowptr[d + 1];
    int e = beg;
    for (; e + 4 <= end; e += 4) {
        int s0 = colidx[e], s1 = colidx[e + 1], s2 = colidx[e + 2], s3 = colidx[e + 3];
        float v0 = g1[(size_t)s0 * HID_DIM + lane];
        float v1 = g1[(size_t)s1 * HID_DIM + lane];
        float v2 = g1[(size_t)s2 * HID_DIM + lane];
        float v3 = g1[(size_t)s3 * HID_DIM + lane];
        acc += v0; acc += v1; acc += v2; acc += v3;
    }
    for (; e < end; ++e) acc += g1[(size_t)colidx[e] * HID_DIM + lane];
    float v = dinv[d] * acc + b1[lane];
    t1[(size_t)d * HID_DIM + lane] = v > 0.f ? v : 0.f;
}

// ---------------------------------------------------------------- agg layer 2
// Two nodes per wave (32 lanes each); writes final output.
__global__ __launch_bounds__(256) void k_agg2(const float* __restrict__ g2,
                                              const int* __restrict__ rowptr,
                                              const int* __restrict__ colidx,
                                              const float* __restrict__ dinv,
                                              const float* __restrict__ b2,
                                              float* __restrict__ out, int N) {
    int d = (blockIdx.x * 256 + threadIdx.x) >> 5;
    int lane = threadIdx.x & 31;
    if (d >= N) return;
    float acc = g2[(size_t)d * OUT_DIM + lane];  // self-loop
    int beg = rowptr[d], end = rowptr[d + 1];
    int e = beg;
    for (; e + 4 <= end; e += 4) {
        int s0 = colidx[e], s1 = colidx[e + 1], s2 = colidx[e + 2], s3 = colidx[e + 3];
        float v0 = g2[(size_t)s0 * OUT_DIM + lane];
        float v1 = g2[(size_t)s1 * OUT_DIM + lane];
        float v2 = g2[(size_t)s2 * OUT_DIM + lane];
        float v3 = g2[(size_t)s3 * OUT_DIM + lane];
        acc += v0; acc += v1; acc += v2; acc += v3;
    }
    for (; e < end; ++e) acc += g2[(size_t)colidx[e] * OUT_DIM + lane];
    out[(size_t)d * OUT_DIM + lane] = dinv[d] * acc + b2[lane];
}

// ---------------------------------------------------------------- launch
extern "C" void kernel_launch(void* const* d_in, const int* in_sizes, int n_in,
                              void* d_out, int out_size, void* d_ws, size_t ws_size,
                              hipStream_t stream) {
    const float* x  = (const float*)d_in[0];
    const int*   ei = (const int*)d_in[1];
    const float* W1 = (const float*)d_in[2];
    const float* b1 = (const float*)d_in[3];
    const float* W2 = (const float*)d_in[4];
    const float* b2 = (const float*)d_in[5];
    float* out = (float*)d_out;

    const int N = in_sizes[0] / IN_DIM;
    const int E = in_sizes[1] / 2;
    const int* src = ei;
    const int* dst = ei + E;

    const int B   = (N + BSIZE - 1) / BSIZE;
    const int nPB = (E + PEB - 1) / PEB;
    const int M   = B * nPB;
    const int nchunks = (M + 1023) / 1024;

    char* p = (char*)d_ws;
    auto alloc = [&](size_t bytes) -> void* {
        void* r = (void*)p;
        p += (bytes + 255) & ~(size_t)255;
        return r;
    };
    int*      mat    = (int*)alloc((size_t)M * 4);
    int*      mats   = (int*)alloc((size_t)M * 4);
    int*      sums   = (int*)alloc((size_t)nchunks * 4);
    unsigned* packed = (unsigned*)alloc((size_t)E * 4);
    int*      colidx = (int*)alloc((size_t)E * 4);
    int*      rowptr = (int*)alloc((size_t)(N + 1) * 4);
    float*    dinv   = (float*)alloc((size_t)N * 4);
    float*    g1     = (float*)alloc((size_t)N * HID_DIM * 4);  // g2 aliases (dead after agg1... actually after gemm2 reads t1; g1 dead after agg1)
    float*    t1     = (float*)alloc((size_t)N * HID_DIM * 4);
    float*    g2     = g1;  // alias: g1 dead once agg1 completes

    k_hist<<<nPB, 256, 0, stream>>>(dst, E, mat, B, nPB);
    k_chunk_sums<<<nchunks, 256, 0, stream>>>(mat, M, sums);
    k_scan_sums<<<1, 1024, 0, stream>>>(sums, nchunks);
    k_scan_chunks<<<nchunks, 256, 0, stream>>>(mat, M, sums, mats);
    k_partition<<<nPB, 256, 0, stream>>>(src, dst, E, mats, packed, B, nPB);
    k_csrfill<<<B, 256, 0, stream>>>(packed, mats, colidx, rowptr, dinv, N, E, B, nPB);

    k_gemm1<<<(N + 63) / 64, 256, 0, stream>>>(x, W1, dinv, g1, N);
    k_agg1<<<(N + 3) / 4, 256, 0, stream>>>(g1, rowptr, colidx, dinv, b1, t1, N);
    k_gemm2<<<(N + 63) / 64, 256, 0, stream>>>(t1, W2, dinv, g2, N);
    k_agg2<<<(N + 7) / 8, 256, 0, stream>>>(g2, rowptr, colidx, dinv, b2, out, N);
}